// Round 13
// baseline (542.447 us; speedup 1.0000x reference)
//
#include <hip/hip_runtime.h>
#include <hip/hip_bf16.h>
#include <math.h>

#define B_ 8
#define L_ 4096
#define C_ 512
#define H_ 2048
#define NPOS_ (B_*L_)

typedef __attribute__((ext_vector_type(8))) short short8;
typedef __attribute__((ext_vector_type(4))) float f32x4;

// counted vmcnt (T4): loads stay in flight across raw barriers
#define VMCNT(n) asm volatile("s_waitcnt vmcnt(" #n ")" ::: "memory")

__device__ __forceinline__ float bf2f(unsigned int u) {
    union { unsigned int u; float f; } c; c.u = u << 16; return c.f;
}
__device__ __forceinline__ unsigned short f2bf(float f) {
    union { float f; unsigned int u; } c; c.f = f;
    unsigned int r = c.u + 0x7fffu + ((c.u >> 16) & 1u);
    return (unsigned short)(r >> 16);
}

// direct global->LDS, 16B/lane. LDS dest = wave-uniform base + lane*16 (linear);
// swizzle achieved by pre-XORing the per-lane GLOBAL source column (rule #21).
__device__ __forceinline__ void gload_lds16(const unsigned short* g, unsigned char* l) {
    __builtin_amdgcn_global_load_lds(
        (const __attribute__((address_space(1))) void*)g,
        (__attribute__((address_space(3))) void*)l, 16, 0, 0);
}

// ---------------- prep kernels ----------------

// conv weight [o][c][k] f32 -> [k][o][c] bf16
__global__ void __launch_bounds__(256) prep_conv_w(const float* __restrict__ W,
                                                   unsigned short* __restrict__ out, int K) {
    int idx = blockIdx.x * 256 + threadIdx.x;
    if (idx >= K * C_ * C_) return;
    int c = idx & (C_ - 1);
    int o = (idx >> 9) & (C_ - 1);
    int k = idx >> 18;
    out[idx] = f2bf(W[((size_t)o * C_ + c) * K + k]);
}

// in [R, Cc] f32 -> out [Cc, R] bf16
__global__ void __launch_bounds__(256) transpose_cast(const float* __restrict__ in,
                                                      unsigned short* __restrict__ out,
                                                      int R, int Cc) {
    __shared__ float tile[32][33];
    int tx = threadIdx.x & 31, ty = threadIdx.x >> 5;
    int c = blockIdx.x * 32 + tx;
    #pragma unroll
    for (int i = 0; i < 32; i += 8) {
        int r = blockIdx.y * 32 + ty + i;
        tile[ty + i][tx] = in[(size_t)r * Cc + c];
    }
    __syncthreads();
    #pragma unroll
    for (int i = 0; i < 32; i += 8) {
        int ro = blockIdx.x * 32 + ty + i;
        int co = blockIdx.y * 32 + tx;
        out[(size_t)ro * R + co] = f2bf(tile[tx][ty + i]);
    }
}

__global__ void __launch_bounds__(256) cast_f32_bf16(const float* __restrict__ in,
                                                     unsigned short* __restrict__ out, int n4) {
    int i = blockIdx.x * 256 + threadIdx.x;
    if (i >= n4) return;
    float4 v = ((const float4*)in)[i];
    uint2 o;
    o.x = (unsigned int)f2bf(v.x) | ((unsigned int)f2bf(v.y) << 16);
    o.y = (unsigned int)f2bf(v.z) | ((unsigned int)f2bf(v.w) << 16);
    ((uint2*)out)[i] = o;
}

// ---------------- masked conv (GEMM over taps) ----------------
// EXACT r12 config (proven 117us K=7): BM=128 x BN=128, 4 waves, wave tile
// 64x64, acc[4][4], 124 VGPR. 3-buffer B rotation, one barrier per tap.
template<int K>
__global__ void __launch_bounds__(256) conv_masked(const unsigned short* __restrict__ in,
                                                   const unsigned short* __restrict__ wt,
                                                   const float* __restrict__ bias,
                                                   const int* __restrict__ ids,
                                                   unsigned short* __restrict__ out) {
    constexpr int PL = (K - 1) / 2;
    constexpr int BM = 128, BN = 128;
    constexpr int ROWS = BM + K - 1;
    constexpr int ACH = (ROWS + 7) / 8;

    __shared__ __align__(16) unsigned char sA[ACH * 1024];
    __shared__ __align__(16) unsigned char sB[3][16 * 1024];
    __shared__ int sIds[ROWS];

    const int tid = threadIdx.x;
    const int wid = tid >> 6, lane = tid & 63;
    const int l15 = lane & 15, l4 = lane >> 4;
    const int r8 = lane >> 3, c8 = lane & 7;
    const int c16s = c8 ^ r8;                    // pre-swizzled source column
    const int i0 = blockIdx.x * BM;
    const int b = i0 >> 12;                      // / L_
    const int i0l = i0 & (L_ - 1);
    const int o0 = blockIdx.y * BN;
    const int wm = wid >> 1, wn = wid & 1;       // 2x2 waves: 64 pos x 64 cout

    for (int r = tid; r < ROWS; r += 256) {
        int il = i0l + r - PL;
        sIds[r] = (il >= 0 && il < L_) ? ids[b * L_ + il] : -1;
    }
    __syncthreads();

    unsigned int mbits[4];
    #pragma unroll
    for (int mf = 0; mf < 4; ++mf) {
        int p = wm * 64 + mf * 16 + l15;
        int ctr = sIds[p + PL];
        unsigned int m = 0;
        #pragma unroll
        for (int k = 0; k < K; ++k)
            if (sIds[p + k] == ctr) m |= (1u << k);
        mbits[mf] = m;
    }

    f32x4 acc[4][4];
    #pragma unroll
    for (int i = 0; i < 4; ++i)
        #pragma unroll
        for (int j = 0; j < 4; ++j) acc[i][j] = 0.f;

    const short8 zero8 = 0;

    for (int cc = 0; cc < 8; ++cc) {
        __builtin_amdgcn_s_barrier();             // prev cc's readers all done
        #pragma unroll
        for (int it = 0; it < 5; ++it) {
            int chunk = wid + it * 4;             // wave-uniform
            if (chunk < ACH) {
                int row = chunk * 8 + r8;
                int il = i0l + row - PL;
                il = il < 0 ? 0 : (il >= L_ ? L_ - 1 : il);
                gload_lds16(in + ((size_t)(b * L_ + il) * C_ + cc * 64 + c16s * 8),
                            sA + chunk * 1024);
            }
        }
        const unsigned short* wcc = wt + (size_t)o0 * C_ + cc * 64;
        #pragma unroll
        for (int it = 0; it < 4; ++it) {
            int chunk = wid * 4 + it;
            int row = chunk * 8 + r8;
            gload_lds16(wcc + (size_t)row * C_ + c16s * 8, sB[0] + chunk * 1024);
        }
        if (K > 1) {
            const unsigned short* w1 = wcc + (size_t)C_ * C_;
            #pragma unroll
            for (int it = 0; it < 4; ++it) {
                int chunk = wid * 4 + it;
                int row = chunk * 8 + r8;
                gload_lds16(w1 + (size_t)row * C_ + c16s * 8, sB[1] + chunk * 1024);
            }
        }

        #pragma unroll
        for (int k = 0; k < K; ++k) {
            if (k + 1 < K) { VMCNT(4); } else { VMCNT(0); }
            __builtin_amdgcn_s_barrier();
            if (k + 2 < K) {                      // stage B_{k+2} (post-barrier)
                const unsigned short* wkb = wcc + (size_t)(k + 2) * C_ * C_;
                unsigned char* dst = sB[(k + 2) % 3];
                #pragma unroll
                for (int it = 0; it < 4; ++it) {
                    int chunk = wid * 4 + it;
                    int row = chunk * 8 + r8;
                    gload_lds16(wkb + (size_t)row * C_ + c16s * 8, dst + chunk * 1024);
                }
            }
            const unsigned char* bbuf = sB[k % 3];
            #pragma unroll
            for (int kk = 0; kk < 2; ++kk) {
                short8 af[4];
                #pragma unroll
                for (int mf = 0; mf < 4; ++mf) {
                    int row = wm * 64 + mf * 16 + l15 + k;
                    int addr = (row * 128 + kk * 64 + l4 * 16) ^ ((row & 7) << 4);
                    short8 a = *(const short8*)(sA + addr);
                    af[mf] = ((mbits[mf] >> k) & 1u) ? a : zero8;
                }
                #pragma unroll
                for (int nf = 0; nf < 4; ++nf) {
                    int col = wn * 64 + nf * 16 + l15;
                    int addr = (col * 128 + kk * 64 + l4 * 16) ^ ((col & 7) << 4);
                    short8 bfr = *(const short8*)(bbuf + addr);
                    #pragma unroll
                    for (int mf = 0; mf < 4; ++mf)
                        acc[mf][nf] = __builtin_amdgcn_mfma_f32_16x16x32_bf16(af[mf], bfr, acc[mf][nf], 0, 0, 0);
                }
            }
        }
    }

    #pragma unroll
    for (int mf = 0; mf < 4; ++mf)
        #pragma unroll
        for (int nf = 0; nf < 4; ++nf) {
            int col = o0 + wn * 64 + nf * 16 + l15;
            float bv = bias[col];
            #pragma unroll
            for (int j = 0; j < 4; ++j) {
                int p = i0 + wm * 64 + mf * 16 + l4 * 4 + j;
                out[(size_t)p * C_ + col] = f2bf(acc[mf][nf][j] + bv);
            }
        }
}

// ---------------- LN kernels ----------------

__global__ void __launch_bounds__(256) ln1_kernel(const float* __restrict__ x,
                                                  const unsigned short* __restrict__ cv,
                                                  const float* __restrict__ g,
                                                  const float* __restrict__ bb,
                                                  unsigned short* __restrict__ hb) {
    __shared__ float red[8];
    int row = blockIdx.x, t = threadIdx.x;
    size_t base = (size_t)row * C_;
    float2 xv = *(const float2*)(x + base + t * 2);
    unsigned int cu = *(const unsigned int*)(cv + base + t * 2);
    float s0 = xv.x + bf2f(cu & 0xffffu);
    float s1 = xv.y + bf2f(cu >> 16);
    float ss = s0 + s1;
    #pragma unroll
    for (int off = 32; off; off >>= 1) ss += __shfl_down(ss, off);
    if ((t & 63) == 0) red[t >> 6] = ss;
    __syncthreads();
    if (t == 0) red[4] = (red[0] + red[1] + red[2] + red[3]) * (1.f / C_);
    __syncthreads();
    float mean = red[4];
    float d0 = s0 - mean, d1 = s1 - mean;
    float vv = d0 * d0 + d1 * d1;
    #pragma unroll
    for (int off = 32; off; off >>= 1) vv += __shfl_down(vv, off);
    if ((t & 63) == 0) red[t >> 6] = vv;
    __syncthreads();
    if (t == 0) red[5] = (red[0] + red[1] + red[2] + red[3]) * (1.f / C_);
    __syncthreads();
    float rstd = rsqrtf(red[5] + 1e-5f);
    float2 gv = *(const float2*)(g + t * 2);
    float2 bv = *(const float2*)(bb + t * 2);
    float h0 = d0 * rstd * gv.x + bv.x;
    float h1 = d1 * rstd * gv.y + bv.y;
    *(unsigned int*)(hb + base + t * 2) =
        (unsigned int)f2bf(h0) | ((unsigned int)f2bf(h1) << 16);
}

// out = LN(y) from bf16 y
__global__ void __launch_bounds__(256) ln2_bf16(const unsigned short* __restrict__ yb,
                                                const float* __restrict__ g,
                                                const float* __restrict__ bb,
                                                float* __restrict__ outp) {
    __shared__ float red[8];
    int row = blockIdx.x, t = threadIdx.x;
    size_t base = (size_t)row * C_;
    unsigned int yu = *(const unsigned int*)(yb + base + t * 2);
    float y0 = bf2f(yu & 0xffffu), y1 = bf2f(yu >> 16);
    float ss = y0 + y1;
    #pragma unroll
    for (int off = 32; off; off >>= 1) ss += __shfl_down(ss, off);
    if ((t & 63) == 0) red[t >> 6] = ss;
    __syncthreads();
    if (t == 0) red[4] = (red[0] + red[1] + red[2] + red[3]) * (1.f / C_);
    __syncthreads();
    float mean = red[4];
    float d0 = y0 - mean, d1 = y1 - mean;
    float vv = d0 * d0 + d1 * d1;
    #pragma unroll
    for (int off = 32; off; off >>= 1) vv += __shfl_down(vv, off);
    if ((t & 63) == 0) red[t >> 6] = vv;
    __syncthreads();
    if (t == 0) red[5] = (red[0] + red[1] + red[2] + red[3]) * (1.f / C_);
    __syncthreads();
    float rstd = rsqrtf(red[5] + 1e-5f);
    float2 gv = *(const float2*)(g + t * 2);
    float2 bv = *(const float2*)(bb + t * 2);
    float2 o;
    o.x = d0 * rstd * gv.x + bv.x;
    o.y = d1 * rstd * gv.y + bv.y;
    *(float2*)(outp + base + t * 2) = o;
}

// ---------------- GEMM (A bf16 [M,Kd], BT bf16 [Nd,Kd]) ----------------
// 1-D grid, n-fastest mapping: consecutive blocks share the A row-panel
// (L2-resident; 16x reuse for gemm0, 4x for gemm1).
// SINGLE barrier per kc (conv-r12 protocol, race-free):
//   vmcnt(0) [only stage(kc) outstanding; had full compute(kc-1) to land]
//   -> s_barrier [orders compute(kc-1) readers before stage(kc+1) overwrite]
//   -> stage(kc+1, other buf) -> compute(kc).
// MODE 0: outp bf16 = gelu(acc + bias[n])  [sigmoid-form, max err 3e-4]
// MODE 1: res_io bf16 (in/out, same element per thread): y = acc + bias + res
template<int MODE, int BM, int BN>
__global__ void __launch_bounds__(256) gemm_bf16(const unsigned short* __restrict__ A,
                                                 const unsigned short* __restrict__ BT,
                                                 const float* __restrict__ bias,
                                                 unsigned short* __restrict__ res_io,
                                                 unsigned short* __restrict__ outp,
                                                 int Nd, int Kd) {
    constexpr int MI = BM / 32, NI = BN / 32;
    __shared__ __align__(16) unsigned char sA[2][BM * 128];
    __shared__ __align__(16) unsigned char sBT[2][BN * 128];
    const int tid = threadIdx.x;
    const int wid = tid >> 6, lane = tid & 63;
    const int l15 = lane & 15, l4 = lane >> 4;
    const int r8 = lane >> 3, c8 = lane & 7;
    const int c16s = c8 ^ r8;
    const int nblk = Nd / BN;
    const int m0 = (blockIdx.x / nblk) * BM;
    const int n0 = (blockIdx.x % nblk) * BN;
    const int wm = wid >> 1, wn = wid & 1;

    f32x4 acc[MI][NI];
    #pragma unroll
    for (int i = 0; i < MI; ++i)
        #pragma unroll
        for (int j = 0; j < NI; ++j) acc[i][j] = 0.f;

    const int nk = Kd / 64;
    auto stage = [&](int kc, int bi) {
        const unsigned short* Ab = A + (size_t)m0 * Kd + kc * 64;
        const unsigned short* Bb = BT + (size_t)n0 * Kd + kc * 64;
        #pragma unroll
        for (int it = 0; it < MI; ++it) {
            int chunk = wid * MI + it;
            int row = chunk * 8 + r8;
            gload_lds16(Ab + (size_t)row * Kd + c16s * 8, sA[bi] + chunk * 1024);
        }
        #pragma unroll
        for (int it = 0; it < NI; ++it) {
            int chunk = wid * NI + it;
            int row = chunk * 8 + r8;
            gload_lds16(Bb + (size_t)row * Kd + c16s * 8, sBT[bi] + chunk * 1024);
        }
    };

    stage(0, 0);
    for (int kc = 0; kc < nk; ++kc) {
        VMCNT(0);                                 // stage(kc) landed (own loads)
        __builtin_amdgcn_s_barrier();             // all waves ready; prev readers done
        if (kc + 1 < nk) stage(kc + 1, (kc + 1) & 1);
        const unsigned char* a_ = sA[kc & 1];
        const unsigned char* b_ = sBT[kc & 1];
        #pragma unroll
        for (int kk = 0; kk < 2; ++kk) {
            short8 af[MI], bf[NI];
            #pragma unroll
            for (int i = 0; i < MI; ++i) {
                int row = wm * (BM / 2) + i * 16 + l15;
                af[i] = *(const short8*)(a_ + ((row * 128 + kk * 64 + l4 * 16) ^ ((row & 7) << 4)));
            }
            #pragma unroll
            for (int j = 0; j < NI; ++j) {
                int col = wn * (BN / 2) + j * 16 + l15;
                bf[j] = *(const short8*)(b_ + ((col * 128 + kk * 64 + l4 * 16) ^ ((col & 7) << 4)));
            }
            #pragma unroll
            for (int i = 0; i < MI; ++i)
                #pragma unroll
                for (int j = 0; j < NI; ++j)
                    acc[i][j] = __builtin_amdgcn_mfma_f32_16x16x32_bf16(af[i], bf[j], acc[i][j], 0, 0, 0);
        }
    }

    #pragma unroll
    for (int i = 0; i < MI; ++i)
        #pragma unroll
        for (int j = 0; j < NI; ++j) {
            int col = n0 + wn * (BN / 2) + j * 16 + l15;
            float bv = bias[col];
            #pragma unroll
            for (int jj = 0; jj < 4; ++jj) {
                int row = m0 + wm * (BM / 2) + i * 16 + l4 * 4 + jj;
                size_t idx = (size_t)row * Nd + col;
                float v = acc[i][j][jj] + bv;
                if (MODE == 0) {
                    // gelu(v) ~= v * sigmoid(2*sqrt(2/pi)*(v + 0.044715 v^3))
                    float e = __expf(v * (1.5957691216057308f
                                          + 0.07135481627f * v * v));
                    float r = __builtin_amdgcn_rcpf(e + 1.0f);
                    v = v * e * r;
                    outp[idx] = f2bf(v);
                } else {
                    v += bf2f((unsigned int)res_io[idx]);
                    res_io[idx] = f2bf(v);
                }
            }
        }
}

// ---------------- launch ----------------
// ws (~46MB): wconv 7.9 | wint 2.1 | woutt 2.1 | hb 33.5
// d_out (67MB) doubles as scratch: conv ping-pong bf16 acts; then hid chunk
// [16384,2048]bf16 (exact fit). gemm1 writes y bf16 IN-PLACE into hb;
// ln2 reads hb, writes final f32 to d_out.

extern "C" void kernel_launch(void* const* d_in, const int* in_sizes, int n_in,
                              void* d_out, int out_size, void* d_ws, size_t ws_size,
                              hipStream_t stream) {
    (void)in_sizes; (void)n_in; (void)out_size; (void)ws_size;
    const float* x    = (const float*)d_in[0];
    const int*   ids  = (const int*)d_in[1];
    const float* cw0  = (const float*)d_in[2];
    const float* cb0  = (const float*)d_in[3];
    const float* cw1  = (const float*)d_in[4];
    const float* cb1  = (const float*)d_in[5];
    const float* cw2  = (const float*)d_in[6];
    const float* cb2  = (const float*)d_in[7];
    const float* w_in = (const float*)d_in[8];
    const float* b_in = (const float*)d_in[9];
    const float* w_out= (const float*)d_in[10];
    const float* b_out= (const float*)d_in[11];
    const float* ln1g = (const float*)d_in[12];
    const float* ln1b = (const float*)d_in[13];
    const float* ln2g = (const float*)d_in[14];
    const float* ln2b = (const float*)d_in[15];

    char* ws = (char*)d_ws;
    size_t off = 0;
    auto alloc = [&](size_t bytes) { void* p = ws + off; off += (bytes + 255) & ~(size_t)255; return p; };
    unsigned short* wconv = (unsigned short*)alloc((size_t)15 * C_ * C_ * 2);
    unsigned short* wint  = (unsigned short*)alloc((size_t)H_ * C_ * 2);
    unsigned short* woutt = (unsigned short*)alloc((size_t)C_ * H_ * 2);
    unsigned short* hb    = (unsigned short*)alloc((size_t)NPOS_ * C_ * 2);

    unsigned short* act0 = (unsigned short*)d_out;
    unsigned short* act1 = act0 + (size_t)NPOS_ * C_;
    unsigned short* hid  = (unsigned short*)d_out;   // [16384, 2048] bf16 chunk
    constexpr int MCH = NPOS_ / 2;

    prep_conv_w<<<(3 * C_ * C_ + 255) / 256, 256, 0, stream>>>(cw0, wconv, 3);
    prep_conv_w<<<(5 * C_ * C_ + 255) / 256, 256, 0, stream>>>(cw1, wconv + (size_t)3 * C_ * C_, 5);
    prep_conv_w<<<(7 * C_ * C_ + 255) / 256, 256, 0, stream>>>(cw2, wconv + (size_t)8 * C_ * C_, 7);
    transpose_cast<<<dim3(H_ / 32, C_ / 32), 256, 0, stream>>>(w_in, wint, C_, H_);
    transpose_cast<<<dim3(C_ / 32, H_ / 32), 256, 0, stream>>>(w_out, woutt, H_, C_);
    cast_f32_bf16<<<(NPOS_ * C_ / 4 + 255) / 256, 256, 0, stream>>>(x, act0, NPOS_ * C_ / 4);

    conv_masked<3><<<dim3(NPOS_ / 128, C_ / 128), 256, 0, stream>>>(act0, wconv, cb0, ids, act1);
    conv_masked<5><<<dim3(NPOS_ / 128, C_ / 128), 256, 0, stream>>>(act1, wconv + (size_t)3 * C_ * C_, cb1, ids, act0);
    conv_masked<7><<<dim3(NPOS_ / 128, C_ / 128), 256, 0, stream>>>(act0, wconv + (size_t)8 * C_ * C_, cb2, ids, act1);

    ln1_kernel<<<NPOS_, 256, 0, stream>>>(x, act1, ln1g, ln1b, hb);

    for (int ch = 0; ch < 2; ++ch) {
        unsigned short* hbc = hb + (size_t)ch * MCH * C_;
        gemm_bf16<0, 128, 128><<<(MCH / 128) * (H_ / 128), 256, 0, stream>>>(
            hbc, wint, b_in, nullptr, hid, H_, C_);
        gemm_bf16<1, 128, 128><<<(MCH / 128) * (C_ / 128), 256, 0, stream>>>(
            hid, woutt, b_out, hbc, nullptr, C_, H_);
    }

    ln2_bf16<<<NPOS_, 256, 0, stream>>>(hb, ln2g, ln2b, (float*)d_out);
}

// Round 14
// 525.618 us; speedup vs baseline: 1.0320x; 1.0320x over previous
//
#include <hip/hip_runtime.h>
#include <hip/hip_bf16.h>
#include <math.h>

#define B_ 8
#define L_ 4096
#define C_ 512
#define H_ 2048
#define NPOS_ (B_*L_)

typedef __attribute__((ext_vector_type(8))) short short8;
typedef __attribute__((ext_vector_type(4))) float f32x4;

// counted vmcnt (T4): loads stay in flight across raw barriers
#define VMCNT(n) asm volatile("s_waitcnt vmcnt(" #n ")" ::: "memory")

__device__ __forceinline__ float bf2f(unsigned int u) {
    union { unsigned int u; float f; } c; c.u = u << 16; return c.f;
}
__device__ __forceinline__ unsigned short f2bf(float f) {
    union { float f; unsigned int u; } c; c.f = f;
    unsigned int r = c.u + 0x7fffu + ((c.u >> 16) & 1u);
    return (unsigned short)(r >> 16);
}

// direct global->LDS, 16B/lane. LDS dest = wave-uniform base + lane*16 (linear);
// swizzle achieved by pre-XORing the per-lane GLOBAL source column (rule #21).
__device__ __forceinline__ void gload_lds16(const unsigned short* g, unsigned char* l) {
    __builtin_amdgcn_global_load_lds(
        (const __attribute__((address_space(1))) void*)g,
        (__attribute__((address_space(3))) void*)l, 16, 0, 0);
}

// ---------------- prep kernels ----------------

// conv weight [o][c][k] f32 -> [k][o][c] bf16
__global__ void __launch_bounds__(256) prep_conv_w(const float* __restrict__ W,
                                                   unsigned short* __restrict__ out, int K) {
    int idx = blockIdx.x * 256 + threadIdx.x;
    if (idx >= K * C_ * C_) return;
    int c = idx & (C_ - 1);
    int o = (idx >> 9) & (C_ - 1);
    int k = idx >> 18;
    out[idx] = f2bf(W[((size_t)o * C_ + c) * K + k]);
}

// in [R, Cc] f32 -> out [Cc, R] bf16
__global__ void __launch_bounds__(256) transpose_cast(const float* __restrict__ in,
                                                      unsigned short* __restrict__ out,
                                                      int R, int Cc) {
    __shared__ float tile[32][33];
    int tx = threadIdx.x & 31, ty = threadIdx.x >> 5;
    int c = blockIdx.x * 32 + tx;
    #pragma unroll
    for (int i = 0; i < 32; i += 8) {
        int r = blockIdx.y * 32 + ty + i;
        tile[ty + i][tx] = in[(size_t)r * Cc + c];
    }
    __syncthreads();
    #pragma unroll
    for (int i = 0; i < 32; i += 8) {
        int ro = blockIdx.x * 32 + ty + i;
        int co = blockIdx.y * 32 + tx;
        out[(size_t)ro * R + co] = f2bf(tile[tx][ty + i]);
    }
}

__global__ void __launch_bounds__(256) cast_f32_bf16(const float* __restrict__ in,
                                                     unsigned short* __restrict__ out, int n4) {
    int i = blockIdx.x * 256 + threadIdx.x;
    if (i >= n4) return;
    float4 v = ((const float4*)in)[i];
    uint2 o;
    o.x = (unsigned int)f2bf(v.x) | ((unsigned int)f2bf(v.y) << 16);
    o.y = (unsigned int)f2bf(v.z) | ((unsigned int)f2bf(v.w) << 16);
    ((uint2*)out)[i] = o;
}

// ---------------- masked conv (GEMM over taps) ----------------
// EXACT r12 config (proven 117us K=7): BM=128 x BN=128, 4 waves, wave tile
// 64x64, acc[4][4], 124 VGPR. 3-buffer B rotation, one barrier per tap.
template<int K>
__global__ void __launch_bounds__(256) conv_masked(const unsigned short* __restrict__ in,
                                                   const unsigned short* __restrict__ wt,
                                                   const float* __restrict__ bias,
                                                   const int* __restrict__ ids,
                                                   unsigned short* __restrict__ out) {
    constexpr int PL = (K - 1) / 2;
    constexpr int BM = 128, BN = 128;
    constexpr int ROWS = BM + K - 1;
    constexpr int ACH = (ROWS + 7) / 8;

    __shared__ __align__(16) unsigned char sA[ACH * 1024];
    __shared__ __align__(16) unsigned char sB[3][16 * 1024];
    __shared__ int sIds[ROWS];

    const int tid = threadIdx.x;
    const int wid = tid >> 6, lane = tid & 63;
    const int l15 = lane & 15, l4 = lane >> 4;
    const int r8 = lane >> 3, c8 = lane & 7;
    const int c16s = c8 ^ r8;                    // pre-swizzled source column
    const int i0 = blockIdx.x * BM;
    const int b = i0 >> 12;                      // / L_
    const int i0l = i0 & (L_ - 1);
    const int o0 = blockIdx.y * BN;
    const int wm = wid >> 1, wn = wid & 1;       // 2x2 waves: 64 pos x 64 cout

    for (int r = tid; r < ROWS; r += 256) {
        int il = i0l + r - PL;
        sIds[r] = (il >= 0 && il < L_) ? ids[b * L_ + il] : -1;
    }
    __syncthreads();

    unsigned int mbits[4];
    #pragma unroll
    for (int mf = 0; mf < 4; ++mf) {
        int p = wm * 64 + mf * 16 + l15;
        int ctr = sIds[p + PL];
        unsigned int m = 0;
        #pragma unroll
        for (int k = 0; k < K; ++k)
            if (sIds[p + k] == ctr) m |= (1u << k);
        mbits[mf] = m;
    }

    f32x4 acc[4][4];
    #pragma unroll
    for (int i = 0; i < 4; ++i)
        #pragma unroll
        for (int j = 0; j < 4; ++j) acc[i][j] = 0.f;

    const short8 zero8 = 0;

    for (int cc = 0; cc < 8; ++cc) {
        __builtin_amdgcn_s_barrier();             // prev cc's readers all done
        #pragma unroll
        for (int it = 0; it < 5; ++it) {
            int chunk = wid + it * 4;             // wave-uniform
            if (chunk < ACH) {
                int row = chunk * 8 + r8;
                int il = i0l + row - PL;
                il = il < 0 ? 0 : (il >= L_ ? L_ - 1 : il);
                gload_lds16(in + ((size_t)(b * L_ + il) * C_ + cc * 64 + c16s * 8),
                            sA + chunk * 1024);
            }
        }
        const unsigned short* wcc = wt + (size_t)o0 * C_ + cc * 64;
        #pragma unroll
        for (int it = 0; it < 4; ++it) {
            int chunk = wid * 4 + it;
            int row = chunk * 8 + r8;
            gload_lds16(wcc + (size_t)row * C_ + c16s * 8, sB[0] + chunk * 1024);
        }
        if (K > 1) {
            const unsigned short* w1 = wcc + (size_t)C_ * C_;
            #pragma unroll
            for (int it = 0; it < 4; ++it) {
                int chunk = wid * 4 + it;
                int row = chunk * 8 + r8;
                gload_lds16(w1 + (size_t)row * C_ + c16s * 8, sB[1] + chunk * 1024);
            }
        }

        #pragma unroll
        for (int k = 0; k < K; ++k) {
            if (k + 1 < K) { VMCNT(4); } else { VMCNT(0); }
            __builtin_amdgcn_s_barrier();
            if (k + 2 < K) {                      // stage B_{k+2} (post-barrier)
                const unsigned short* wkb = wcc + (size_t)(k + 2) * C_ * C_;
                unsigned char* dst = sB[(k + 2) % 3];
                #pragma unroll
                for (int it = 0; it < 4; ++it) {
                    int chunk = wid * 4 + it;
                    int row = chunk * 8 + r8;
                    gload_lds16(wkb + (size_t)row * C_ + c16s * 8, dst + chunk * 1024);
                }
            }
            const unsigned char* bbuf = sB[k % 3];
            #pragma unroll
            for (int kk = 0; kk < 2; ++kk) {
                short8 af[4];
                #pragma unroll
                for (int mf = 0; mf < 4; ++mf) {
                    int row = wm * 64 + mf * 16 + l15 + k;
                    int addr = (row * 128 + kk * 64 + l4 * 16) ^ ((row & 7) << 4);
                    short8 a = *(const short8*)(sA + addr);
                    af[mf] = ((mbits[mf] >> k) & 1u) ? a : zero8;
                }
                #pragma unroll
                for (int nf = 0; nf < 4; ++nf) {
                    int col = wn * 64 + nf * 16 + l15;
                    int addr = (col * 128 + kk * 64 + l4 * 16) ^ ((col & 7) << 4);
                    short8 bfr = *(const short8*)(bbuf + addr);
                    #pragma unroll
                    for (int mf = 0; mf < 4; ++mf)
                        acc[mf][nf] = __builtin_amdgcn_mfma_f32_16x16x32_bf16(af[mf], bfr, acc[mf][nf], 0, 0, 0);
                }
            }
        }
    }

    #pragma unroll
    for (int mf = 0; mf < 4; ++mf)
        #pragma unroll
        for (int nf = 0; nf < 4; ++nf) {
            int col = o0 + wn * 64 + nf * 16 + l15;
            float bv = bias[col];
            #pragma unroll
            for (int j = 0; j < 4; ++j) {
                int p = i0 + wm * 64 + mf * 16 + l4 * 4 + j;
                out[(size_t)p * C_ + col] = f2bf(acc[mf][nf][j] + bv);
            }
        }
}

// ---------------- LN kernels ----------------

// h = LN(xb + cv) — both bf16 (xb is the pre-cast copy of x; saves the
// 134MB f32 x re-read; adds one bf16 rounding to the residual, ~+0.008 abs)
__global__ void __launch_bounds__(256) ln1_kernel(const unsigned short* __restrict__ xb,
                                                  const unsigned short* __restrict__ cv,
                                                  const float* __restrict__ g,
                                                  const float* __restrict__ bb,
                                                  unsigned short* __restrict__ hb) {
    __shared__ float red[8];
    int row = blockIdx.x, t = threadIdx.x;
    size_t base = (size_t)row * C_;
    unsigned int xu = *(const unsigned int*)(xb + base + t * 2);
    unsigned int cu = *(const unsigned int*)(cv + base + t * 2);
    float s0 = bf2f(xu & 0xffffu) + bf2f(cu & 0xffffu);
    float s1 = bf2f(xu >> 16) + bf2f(cu >> 16);
    float ss = s0 + s1;
    #pragma unroll
    for (int off = 32; off; off >>= 1) ss += __shfl_down(ss, off);
    if ((t & 63) == 0) red[t >> 6] = ss;
    __syncthreads();
    if (t == 0) red[4] = (red[0] + red[1] + red[2] + red[3]) * (1.f / C_);
    __syncthreads();
    float mean = red[4];
    float d0 = s0 - mean, d1 = s1 - mean;
    float vv = d0 * d0 + d1 * d1;
    #pragma unroll
    for (int off = 32; off; off >>= 1) vv += __shfl_down(vv, off);
    if ((t & 63) == 0) red[t >> 6] = vv;
    __syncthreads();
    if (t == 0) red[5] = (red[0] + red[1] + red[2] + red[3]) * (1.f / C_);
    __syncthreads();
    float rstd = rsqrtf(red[5] + 1e-5f);
    float2 gv = *(const float2*)(g + t * 2);
    float2 bv = *(const float2*)(bb + t * 2);
    float h0 = d0 * rstd * gv.x + bv.x;
    float h1 = d1 * rstd * gv.y + bv.y;
    *(unsigned int*)(hb + base + t * 2) =
        (unsigned int)f2bf(h0) | ((unsigned int)f2bf(h1) << 16);
}

// out = LN(y) from bf16 y
__global__ void __launch_bounds__(256) ln2_bf16(const unsigned short* __restrict__ yb,
                                                const float* __restrict__ g,
                                                const float* __restrict__ bb,
                                                float* __restrict__ outp) {
    __shared__ float red[8];
    int row = blockIdx.x, t = threadIdx.x;
    size_t base = (size_t)row * C_;
    unsigned int yu = *(const unsigned int*)(yb + base + t * 2);
    float y0 = bf2f(yu & 0xffffu), y1 = bf2f(yu >> 16);
    float ss = y0 + y1;
    #pragma unroll
    for (int off = 32; off; off >>= 1) ss += __shfl_down(ss, off);
    if ((t & 63) == 0) red[t >> 6] = ss;
    __syncthreads();
    if (t == 0) red[4] = (red[0] + red[1] + red[2] + red[3]) * (1.f / C_);
    __syncthreads();
    float mean = red[4];
    float d0 = y0 - mean, d1 = y1 - mean;
    float vv = d0 * d0 + d1 * d1;
    #pragma unroll
    for (int off = 32; off; off >>= 1) vv += __shfl_down(vv, off);
    if ((t & 63) == 0) red[t >> 6] = vv;
    __syncthreads();
    if (t == 0) red[5] = (red[0] + red[1] + red[2] + red[3]) * (1.f / C_);
    __syncthreads();
    float rstd = rsqrtf(red[5] + 1e-5f);
    float2 gv = *(const float2*)(g + t * 2);
    float2 bv = *(const float2*)(bb + t * 2);
    float2 o;
    o.x = d0 * rstd * gv.x + bv.x;
    o.y = d1 * rstd * gv.y + bv.y;
    *(float2*)(outp + base + t * 2) = o;
}

// ---------------- GEMM (A bf16 [M,Kd], BT bf16 [Nd,Kd]) ----------------
// EXACT r12 structure (counted vmcnt, two barriers/kc — r13's single-barrier
// vmcnt(0) variant regressed):
//   STAGE(kc+1) -> vmcnt(LPW) -> barrier -> compute(kc) -> barrier.
// MODE 0: outp bf16 = gelu(acc + bias[n])  [sigmoid-form, max err 3e-4]
// MODE 1: res_io bf16 (in/out, same element per thread): y = acc + bias + res
template<int MODE, int BM, int BN>
__global__ void __launch_bounds__(256) gemm_bf16(const unsigned short* __restrict__ A,
                                                 const unsigned short* __restrict__ BT,
                                                 const float* __restrict__ bias,
                                                 unsigned short* __restrict__ res_io,
                                                 unsigned short* __restrict__ outp,
                                                 int Nd, int Kd) {
    constexpr int MI = BM / 32, NI = BN / 32;
    __shared__ __align__(16) unsigned char sA[2][BM * 128];
    __shared__ __align__(16) unsigned char sBT[2][BN * 128];
    const int tid = threadIdx.x;
    const int wid = tid >> 6, lane = tid & 63;
    const int l15 = lane & 15, l4 = lane >> 4;
    const int r8 = lane >> 3, c8 = lane & 7;
    const int c16s = c8 ^ r8;
    const int m0 = blockIdx.x * BM, n0 = blockIdx.y * BN;
    const int wm = wid >> 1, wn = wid & 1;

    f32x4 acc[MI][NI];
    #pragma unroll
    for (int i = 0; i < MI; ++i)
        #pragma unroll
        for (int j = 0; j < NI; ++j) acc[i][j] = 0.f;

    const int nk = Kd / 64;
    auto stage = [&](int kc, int bi) {
        const unsigned short* Ab = A + (size_t)m0 * Kd + kc * 64;
        const unsigned short* Bb = BT + (size_t)n0 * Kd + kc * 64;
        #pragma unroll
        for (int it = 0; it < MI; ++it) {
            int chunk = wid * MI + it;
            int row = chunk * 8 + r8;
            gload_lds16(Ab + (size_t)row * Kd + c16s * 8, sA[bi] + chunk * 1024);
        }
        #pragma unroll
        for (int it = 0; it < NI; ++it) {
            int chunk = wid * NI + it;
            int row = chunk * 8 + r8;
            gload_lds16(Bb + (size_t)row * Kd + c16s * 8, sBT[bi] + chunk * 1024);
        }
    };

    stage(0, 0);
    for (int kc = 0; kc < nk; ++kc) {
        if (kc + 1 < nk) {
            stage(kc + 1, (kc + 1) & 1);
            if constexpr (MI + NI == 8) VMCNT(8); else VMCNT(6);
        } else {
            VMCNT(0);
        }
        __builtin_amdgcn_s_barrier();
        const unsigned char* a_ = sA[kc & 1];
        const unsigned char* b_ = sBT[kc & 1];
        #pragma unroll
        for (int kk = 0; kk < 2; ++kk) {
            short8 af[MI], bf[NI];
            #pragma unroll
            for (int i = 0; i < MI; ++i) {
                int row = wm * (BM / 2) + i * 16 + l15;
                af[i] = *(const short8*)(a_ + ((row * 128 + kk * 64 + l4 * 16) ^ ((row & 7) << 4)));
            }
            #pragma unroll
            for (int j = 0; j < NI; ++j) {
                int col = wn * (BN / 2) + j * 16 + l15;
                bf[j] = *(const short8*)(b_ + ((col * 128 + kk * 64 + l4 * 16) ^ ((col & 7) << 4)));
            }
            #pragma unroll
            for (int i = 0; i < MI; ++i)
                #pragma unroll
                for (int j = 0; j < NI; ++j)
                    acc[i][j] = __builtin_amdgcn_mfma_f32_16x16x32_bf16(af[i], bf[j], acc[i][j], 0, 0, 0);
        }
        __builtin_amdgcn_s_barrier();
    }

    #pragma unroll
    for (int i = 0; i < MI; ++i)
        #pragma unroll
        for (int j = 0; j < NI; ++j) {
            int col = n0 + wn * (BN / 2) + j * 16 + l15;
            float bv = bias[col];
            #pragma unroll
            for (int jj = 0; jj < 4; ++jj) {
                int row = m0 + wm * (BM / 2) + i * 16 + l4 * 4 + jj;
                size_t idx = (size_t)row * Nd + col;
                float v = acc[i][j][jj] + bv;
                if (MODE == 0) {
                    // gelu(v) ~= v * sigmoid(2*sqrt(2/pi)*(v + 0.044715 v^3))
                    float e = __expf(v * (1.5957691216057308f
                                          + 0.07135481627f * v * v));
                    float r = __builtin_amdgcn_rcpf(e + 1.0f);
                    v = v * e * r;
                    outp[idx] = f2bf(v);
                } else {
                    v += bf2f((unsigned int)res_io[idx]);
                    res_io[idx] = f2bf(v);
                }
            }
        }
}

// ---------------- launch ----------------
// ws (~79MB): wconv 7.9 | wint 2.1 | woutt 2.1 | hb 33.5 | xb 33.5
// d_out (67MB) doubles as scratch: conv ping-pong bf16 acts; then hid chunk
// [16384,2048]bf16 (exact fit). gemm1 writes y bf16 IN-PLACE into hb;
// ln2 reads hb, writes final f32 to d_out.

extern "C" void kernel_launch(void* const* d_in, const int* in_sizes, int n_in,
                              void* d_out, int out_size, void* d_ws, size_t ws_size,
                              hipStream_t stream) {
    (void)in_sizes; (void)n_in; (void)out_size; (void)ws_size;
    const float* x    = (const float*)d_in[0];
    const int*   ids  = (const int*)d_in[1];
    const float* cw0  = (const float*)d_in[2];
    const float* cb0  = (const float*)d_in[3];
    const float* cw1  = (const float*)d_in[4];
    const float* cb1  = (const float*)d_in[5];
    const float* cw2  = (const float*)d_in[6];
    const float* cb2  = (const float*)d_in[7];
    const float* w_in = (const float*)d_in[8];
    const float* b_in = (const float*)d_in[9];
    const float* w_out= (const float*)d_in[10];
    const float* b_out= (const float*)d_in[11];
    const float* ln1g = (const float*)d_in[12];
    const float* ln1b = (const float*)d_in[13];
    const float* ln2g = (const float*)d_in[14];
    const float* ln2b = (const float*)d_in[15];

    char* ws = (char*)d_ws;
    size_t off = 0;
    auto alloc = [&](size_t bytes) { void* p = ws + off; off += (bytes + 255) & ~(size_t)255; return p; };
    unsigned short* wconv = (unsigned short*)alloc((size_t)15 * C_ * C_ * 2);
    unsigned short* wint  = (unsigned short*)alloc((size_t)H_ * C_ * 2);
    unsigned short* woutt = (unsigned short*)alloc((size_t)C_ * H_ * 2);
    unsigned short* hb    = (unsigned short*)alloc((size_t)NPOS_ * C_ * 2);
    unsigned short* xb    = (unsigned short*)alloc((size_t)NPOS_ * C_ * 2);

    unsigned short* act0 = (unsigned short*)d_out;
    unsigned short* act1 = act0 + (size_t)NPOS_ * C_;
    unsigned short* hid  = (unsigned short*)d_out;   // [16384, 2048] bf16 chunk
    constexpr int MCH = NPOS_ / 2;

    prep_conv_w<<<(3 * C_ * C_ + 255) / 256, 256, 0, stream>>>(cw0, wconv, 3);
    prep_conv_w<<<(5 * C_ * C_ + 255) / 256, 256, 0, stream>>>(cw1, wconv + (size_t)3 * C_ * C_, 5);
    prep_conv_w<<<(7 * C_ * C_ + 255) / 256, 256, 0, stream>>>(cw2, wconv + (size_t)8 * C_ * C_, 7);
    transpose_cast<<<dim3(H_ / 32, C_ / 32), 256, 0, stream>>>(w_in, wint, C_, H_);
    transpose_cast<<<dim3(C_ / 32, H_ / 32), 256, 0, stream>>>(w_out, woutt, H_, C_);
    cast_f32_bf16<<<(NPOS_ * C_ / 4 + 255) / 256, 256, 0, stream>>>(x, xb, NPOS_ * C_ / 4);

    conv_masked<3><<<dim3(NPOS_ / 128, C_ / 128), 256, 0, stream>>>(xb, wconv, cb0, ids, act0);
    conv_masked<5><<<dim3(NPOS_ / 128, C_ / 128), 256, 0, stream>>>(act0, wconv + (size_t)3 * C_ * C_, cb1, ids, act1);
    conv_masked<7><<<dim3(NPOS_ / 128, C_ / 128), 256, 0, stream>>>(act1, wconv + (size_t)8 * C_ * C_, cb2, ids, act0);

    ln1_kernel<<<NPOS_, 256, 0, stream>>>(xb, act0, ln1g, ln1b, hb);

    for (int ch = 0; ch < 2; ++ch) {
        unsigned short* hbc = hb + (size_t)ch * MCH * C_;
        gemm_bf16<0, 128, 128><<<dim3(MCH / 128, H_ / 128), 256, 0, stream>>>(
            hbc, wint, b_in, nullptr, hid, H_, C_);
        gemm_bf16<1, 128, 128><<<dim3(MCH / 128, C_ / 128), 256, 0, stream>>>(
            hid, woutt, b_out, hbc, nullptr, C_, H_);
    }

    ln2_bf16<<<NPOS_, 256, 0, stream>>>(hb, ln2g, ln2b, (float*)d_out);
}